// Round 1
// baseline (534.621 us; speedup 1.0000x reference)
//
#include <hip/hip_runtime.h>
#include <math.h>

// CTC-CRF NLL: mean_b( logZ_den(b) - logZ_num(b) )
// B=16, T=2048, S=8, L=256 (read generically from in_sizes).
//
// All log-domain math is done in BASE-2 (inputs scaled by log2(e) once at
// staging time) so logaddexp maps directly onto v_exp_f32 / v_log_f32.
// Final result is scaled back by ln(2).
//
// Grid of 2B blocks: blocks [0,B) numerator (256 thr = 1 lattice pos each),
// blocks [B,2B) denominator (1 wave, lane j = state j). Both stage the
// batch's emissions (T*S*4 = 64 KiB) into dynamic LDS.
//
// Numerator cross-wave u-1 exchange: 16-float double-buffered LDS slot
// aliased onto em rows 0-1 (dead after t=1; t=1 boundary values are
// provably NEG since only u=0 is live at t=0). One __syncthreads per step:
//   write bnd[parity] -> barrier -> read bnd[parity]; the next step writes
//   the opposite parity, and the barrier at t+1 orders the t+2 rewrite
//   after all t reads. Race-free with a single barrier.

#define NEGV  (-1e30f)
#define LOG2E 1.4426950408889634f
#define LN2   0.69314718055994531f
#define NT    256

__device__ __forceinline__ float fexp2(float x) {
#if __has_builtin(__builtin_amdgcn_exp2f)
    return __builtin_amdgcn_exp2f(x);   // v_exp_f32
#else
    return exp2f(x);
#endif
}

__device__ __forceinline__ float flog2(float x) {
#if __has_builtin(__builtin_amdgcn_logf)
    return __builtin_amdgcn_logf(x);    // v_log_f32 (base-2)
#else
    return __log2f(x);
#endif
}

// logaddexp in base-2 domain: log2(2^a + 2^b)
__device__ __forceinline__ float lse2(float a, float b) {
    float m = fmaxf(a, b);
    float d = fminf(a, b) - m;          // <= 0; exp2 underflows cleanly for NEG
    return m + flog2(1.0f + fexp2(d));
}

extern "C" __global__ void __launch_bounds__(NT)
crf_main(const float* __restrict__ em,
         const float* __restrict__ trans,
         const float* __restrict__ bos,
         const float* __restrict__ eos,
         const int*   __restrict__ lengths,
         const int*   __restrict__ targets,
         const int*   __restrict__ tlens,
         float*       __restrict__ ws,
         int B, int T, int S, int L)
{
    extern __shared__ float sm[];            // T*S floats: em[b] * LOG2E
    const int bid = blockIdx.x;
    const int tid = threadIdx.x;
    const bool is_den = (bid >= B);
    const int b = is_den ? (bid - B) : bid;
    const int TS = T * S;
    const float* gem = em + (long)b * TS;

    // ---- stage emissions into LDS, scaled to base-2 log domain ----
    {
        const float4* g4 = (const float4*)gem;
        float4* s4 = (float4*)sm;
        for (int i = tid; i < (TS >> 2); i += NT) {
            float4 v = g4[i];
            v.x *= LOG2E; v.y *= LOG2E; v.z *= LOG2E; v.w *= LOG2E;
            s4[i] = v;
        }
    }
    __syncthreads();

    const int len  = lengths[b];
    const int half = S >> 1;                 // extend-state offset (=4)

    if (!is_den) {
        // ================= numerator: thread = lattice position u ========
        const int u    = tid;
        const int lane = tid & 63;
        const int w    = tid >> 6;           // wave id within block
        int e0 = 0, ep = 0;
        if (u < L) {
            e0 = targets[(long)b * L + u];
            ep = (u > 0) ? targets[(long)b * L + u - 1] : e0;
        }
        const float tee = trans[ep * S + e0] * LOG2E;           // enter_{u-1}->enter_u
        const float txe = trans[(ep + half) * S + e0] * LOG2E;  // extend_{u-1}->enter_u
        const float tex = trans[e0 * S + e0 + half] * LOG2E;    // enter_u->extend_u
        const float txx = trans[(e0 + half) * S + e0 + half] * LOG2E; // extend->extend

        float a_e = (u == 0) ? (bos[e0] * LOG2E + sm[e0]) : NEGV;
        float a_x = NEGV;

        float* bnd = sm;  // 16 floats over em rows 0-1 (dead after t=1)

        for (int t = 1; t < len; ++t) {
            // em reads BEFORE barrier: at t==1 this reads row 1 before any
            // t==2 bnd write (ordered by the t==1 barrier) can clobber it.
            const float em_e = sm[t * S + e0];
            const float em_x = sm[t * S + e0 + half];
            const int p = (t & 1) << 3;      // parity slot base (0 or 8)
            if (t >= 2 && lane == 63) {      // publish carry for next wave
                bnd[p + w]     = a_e;
                bnd[p + 4 + w] = a_x;
            }
            __syncthreads();
            float se = __shfl_up(a_e, 1, 64);
            float sx = __shfl_up(a_x, 1, 64);
            if (lane == 0) {
                const bool ok = (w > 0) && (t >= 2); // t==1 boundaries are NEG
                se = ok ? bnd[p + w - 1]     : NEGV;
                sx = ok ? bnd[p + 4 + w - 1] : NEGV;
            }
            const float ne = em_e + lse2(se + tee, sx + txe);
            const float nx = em_x + lse2(a_e + tex, a_x + txx);
            a_e = ne; a_x = nx;
        }
        const int uf = tlens[b] - 1;
        if (u == uf) {
            const float fe = a_e + eos[e0] * LOG2E;
            const float fx = a_x + eos[e0 + half] * LOG2E;
            ws[b] = lse2(fe, fx);            // logZ_num in base-2
        }
    } else {
        // ================= denominator: lane j = state j (S==8) ==========
        if (tid >= 64) return;               // no further barriers below
        const int j = tid & (S - 1);         // lanes 8..63 mirror harmlessly
        float tcol[8];
#pragma unroll
        for (int i = 0; i < 8; ++i) tcol[i] = trans[i * S + j] * LOG2E;

        float alpha = bos[j] * LOG2E + sm[j];
        for (int t = 1; t < len; ++t) {
            float v[8];
#pragma unroll
            for (int i = 0; i < 8; ++i) v[i] = __shfl(alpha, i, 64) + tcol[i];
            float m = v[0];
#pragma unroll
            for (int i = 1; i < 8; ++i) m = fmaxf(m, v[i]);
            float s = 0.0f;
#pragma unroll
            for (int i = 0; i < 8; ++i) s += fexp2(v[i] - m);
            alpha = m + flog2(s) + sm[t * S + j];
        }
        float f = alpha + eos[j] * LOG2E;
        f = lse2(f, __shfl_xor(f, 1, 64));
        f = lse2(f, __shfl_xor(f, 2, 64));
        f = lse2(f, __shfl_xor(f, 4, 64));
        if (tid == 0) ws[B + b] = f;         // logZ_den in base-2
    }
}

extern "C" __global__ void crf_finalize(const float* __restrict__ ws,
                                        float* __restrict__ out, int B)
{
    const int tid = threadIdx.x;
    float v = (tid < B) ? (ws[B + tid] - ws[tid]) : 0.0f;
#pragma unroll
    for (int o = 32; o > 0; o >>= 1) v += __shfl_down(v, o, 64);
    if (tid == 0) out[0] = v * (LN2 / (float)B);
}

extern "C" void kernel_launch(void* const* d_in, const int* in_sizes, int n_in,
                              void* d_out, int out_size, void* d_ws, size_t ws_size,
                              hipStream_t stream)
{
    const float* em      = (const float*)d_in[0];
    const float* trans   = (const float*)d_in[1];
    const float* bos     = (const float*)d_in[2];
    const float* eos     = (const float*)d_in[3];
    const int*   lengths = (const int*)d_in[4];
    const int*   targets = (const int*)d_in[5];
    const int*   tlens   = (const int*)d_in[6];
    float* out = (float*)d_out;
    float* ws  = (float*)d_ws;

    const int B  = in_sizes[4];               // 16
    const int SS = in_sizes[1];               // S*S = 64
    int S = 1; while (S * S < SS) ++S;        // S = 8
    const int T = in_sizes[0] / (B * S);      // 2048
    const int L = in_sizes[5] / B;            // 256

    const size_t shmem = (size_t)T * S * sizeof(float);  // 64 KiB exactly

    hipLaunchKernelGGL(crf_main, dim3(2 * B), dim3(NT), shmem, stream,
                       em, trans, bos, eos, lengths, targets, tlens, ws,
                       B, T, S, L);
    hipLaunchKernelGGL(crf_finalize, dim3(1), dim3(64), 0, stream, ws, out, B);
}

// Round 3
// 414.143 us; speedup vs baseline: 1.2909x; 1.2909x over previous
//
#include <hip/hip_runtime.h>
#include <math.h>

// CTC-CRF NLL: mean_b( logZ_den(b) - logZ_num(b) ), B=16,T=2048,S=8,L=256.
//
// R2: barrier-free, prob-domain with per-lane block floating point.
//  * Numerator (blocks [0,B)): ONE WAVE per batch, 4 lattice positions per
//    lane. Cross-lane u-1 neighbor via __shfl_up; per-lane int exponent s;
//    renorm every 4 steps. OVERFLOW-PROOF handoff: if neighbor scale gap
//    d = bs - s > 50, lane adopts neighbor scale (s += d, state *= 2^-d)
//    before the ldexp injection -> injection exponent is always <= 50,
//    never inf. Epilogue uses -3e38 sentinels instead of -inf (no inf-inf).
//  * Denominator (blocks [B,2B)): serial prob-domain, lane j = state j
//    (mirrored x8 across the wave), 8 shfl + 8 fma + renorm/4 per step.
//    Strictly positive chain -> no NaN paths. Runs concurrently with num.
//  * ws usage: 2B floats only.

#define LOG2E 1.4426950408889634f
#define LN2   0.69314718055994531f

__device__ __forceinline__ float fexp2(float x) {
#if __has_builtin(__builtin_amdgcn_exp2f)
    return __builtin_amdgcn_exp2f(x);
#else
    return exp2f(x);
#endif
}
__device__ __forceinline__ float flog2(float x) {
#if __has_builtin(__builtin_amdgcn_logf)
    return __builtin_amdgcn_logf(x);
#else
    return __log2f(x);
#endif
}
// log2(2^a + 2^b), safe for -3e38 sentinels (never produces NaN)
__device__ __forceinline__ float lse2(float a, float b) {
    float m = fmaxf(a, b);
    float d = fminf(a, b) - m;
    return m + flog2(1.0f + fexp2(d));
}

extern "C" __global__ void __launch_bounds__(64)
crf_fwd(const float* __restrict__ em, const float* __restrict__ trans,
        const float* __restrict__ bos, const float* __restrict__ eos,
        const int* __restrict__ lengths, const int* __restrict__ targets,
        const int* __restrict__ tlens, float* __restrict__ ws,
        int B, int T, int S, int L)
{
    extern __shared__ float sm[];
    const int bid  = blockIdx.x;
    const int lane = threadIdx.x;            // one wave per block
    const int half = S >> 1;                 // = 4
    const bool is_den = (bid >= B);
    const int b = is_den ? (bid - B) : bid;
    const float* gem = em + (size_t)b * T * S;
    const int len = lengths[b];

    if (!is_den) {
        // ======================= NUMERATOR =======================
        // Stage emissions as base-2 probs, interleaved (enter_j, extend_j)
        // float2 pairs: sm2[t*4 + j] = (2^em[t][j], 2^em[t][j+4]), j in [0,4).
        for (int t = lane; t < T; t += 64) {
            const float4* gr = (const float4*)(gem + t * S);
            float4 a = gr[0], c = gr[1];
            float4 w0, w1;
            w0.x = fexp2(a.x * LOG2E); w0.y = fexp2(c.x * LOG2E);
            w0.z = fexp2(a.y * LOG2E); w0.w = fexp2(c.y * LOG2E);
            w1.x = fexp2(a.z * LOG2E); w1.y = fexp2(c.z * LOG2E);
            w1.z = fexp2(a.w * LOG2E); w1.w = fexp2(c.w * LOG2E);
            ((float4*)sm)[t * 2]     = w0;
            ((float4*)sm)[t * 2 + 1] = w1;
        }
        __syncthreads();
        const float2* sm2 = (const float2*)sm;

        // Per-sub-position constants (u = lane*4 + k); targets are in [0,4).
        const int u0 = lane * 4;
        int e[4], ep[4];
        {
            const int base = b * L;
#pragma unroll
            for (int k = 0; k < 4; ++k) {
                int u = u0 + k;
                e[k] = targets[base + ((u < L) ? u : (L - 1))];
            }
            ep[0] = (u0 > 0) ? targets[base + u0 - 1] : e[0];
            ep[1] = e[0]; ep[2] = e[1]; ep[3] = e[2];
        }
        float tee[4], txe[4], tex[4], txx[4];
#pragma unroll
        for (int k = 0; k < 4; ++k) {
            tee[k] = fexp2(trans[ep[k] * S + e[k]] * LOG2E);
            txe[k] = fexp2(trans[(ep[k] + half) * S + e[k]] * LOG2E);
            tex[k] = fexp2(trans[e[k] * S + e[k] + half] * LOG2E);
            txx[k] = fexp2(trans[(e[k] + half) * S + e[k] + half] * LOG2E);
        }

        float E[4] = {0.f, 0.f, 0.f, 0.f}, X[4] = {0.f, 0.f, 0.f, 0.f};
        int s = 0;                           // per-lane base-2 exponent
        if (lane == 0) E[0] = fexp2((bos[e[0]] + gem[e[0]]) * LOG2E);

        float2 p[4];
#pragma unroll
        for (int k = 0; k < 4; ++k) p[k] = sm2[4 + e[k]];   // t = 1

        for (int t = 1; t < len; ++t) {
            const int tn = (t + 1 < len) ? t + 1 : t;        // prefetch t+1
            float2 n0 = sm2[tn * 4 + e[0]];
            float2 n1 = sm2[tn * 4 + e[1]];
            float2 n2 = sm2[tn * 4 + e[2]];
            float2 n3 = sm2[tn * 4 + e[3]];

            float bE = __shfl_up(E[3], 1);
            float bX = __shfl_up(X[3], 1);
            int   bs = __shfl_up(s, 1);
            int d = (lane == 0) ? 0 : (bs - s);
            // Overflow-proof rebase: if the incoming scale dwarfs this
            // lane's, adopt the neighbor scale (exact shrink of own state;
            // flushes only mass >= 2^50 below the incoming value).
            if (__ballot(d > 50)) {
                const int up = (d > 50) ? d : 0;
                s += up;
                const float f = ldexpf(1.0f, -up);  // 0 if up > ~170: fine
#pragma unroll
                for (int k = 0; k < 4; ++k) { E[k] *= f; X[k] *= f; }
                d -= up;
            }
            // d <= 50 now; very negative d underflows to 0 harmlessly.
            float inE = (lane == 0) ? 0.0f : ldexpf(bE, d);
            float inX = (lane == 0) ? 0.0f : ldexpf(bX, d);

            float nE0 = p[0].x * fmaf(inE,  tee[0], inX  * txe[0]);
            float nE1 = p[1].x * fmaf(E[0], tee[1], X[0] * txe[1]);
            float nE2 = p[2].x * fmaf(E[1], tee[2], X[1] * txe[2]);
            float nE3 = p[3].x * fmaf(E[2], tee[3], X[2] * txe[3]);
            float nX0 = p[0].y * fmaf(E[0], tex[0], X[0] * txx[0]);
            float nX1 = p[1].y * fmaf(E[1], tex[1], X[1] * txx[1]);
            float nX2 = p[2].y * fmaf(E[2], tex[2], X[2] * txx[2]);
            float nX3 = p[3].y * fmaf(E[3], tex[3], X[3] * txx[3]);
            E[0] = nE0; E[1] = nE1; E[2] = nE2; E[3] = nE3;
            X[0] = nX0; X[1] = nX1; X[2] = nX2; X[3] = nX3;
            p[0] = n0; p[1] = n1; p[2] = n2; p[3] = n3;

            if ((t & 3) == 0) {              // per-lane renorm, every 4
                float m = fmaxf(fmaxf(fmaxf(E[0], E[1]), fmaxf(E[2], E[3])),
                                fmaxf(fmaxf(X[0], X[1]), fmaxf(X[2], X[3])));
                if (m > 0.0f) {
                    const int ex = (int)(__float_as_uint(m) >> 23) - 126;
                    s += ex;
                    const float f = ldexpf(1.0f, -ex);
#pragma unroll
                    for (int k = 0; k < 4; ++k) { E[k] *= f; X[k] *= f; }
                } else {
                    s = bs;                  // dead lane tracks neighbor
                }
            }
        }

        const int uf = tlens[b] - 1;
        if (lane == (uf >> 2)) {
            const int k = uf & 3;
            const float fE = (k == 0) ? E[0] : (k == 1) ? E[1] : (k == 2) ? E[2] : E[3];
            const float fX = (k == 0) ? X[0] : (k == 1) ? X[1] : (k == 2) ? X[2] : X[3];
            const int  ek = (k == 0) ? e[0] : (k == 1) ? e[1] : (k == 2) ? e[2] : e[3];
            const float le = (fE > 1e-36f)
                ? flog2(fE) + (float)s + eos[ek] * LOG2E : -3.0e38f;
            const float lx = (fX > 1e-36f)
                ? flog2(fX) + (float)s + eos[ek + half] * LOG2E : -3.0e38f;
            ws[b] = lse2(le, lx);            // logZ_num, base 2
        }
    } else {
        // ======================= DENOMINATOR =======================
        // Serial prob-domain forward; lane j = tid&7 (mirrored x8 so
        // __shfl(al, i) for i in [0,8) reads valid identical copies).
        for (int idx = lane; idx < T * 2; idx += 64) {   // float4 granules
            float4 v = ((const float4*)gem)[idx];
            float4 w;
            w.x = fexp2(v.x * LOG2E); w.y = fexp2(v.y * LOG2E);
            w.z = fexp2(v.z * LOG2E); w.w = fexp2(v.w * LOG2E);
            ((float4*)sm)[idx] = w;
        }
        __syncthreads();

        const int j = lane & (S - 1);
        float Tp[8];
#pragma unroll
        for (int i = 0; i < 8; ++i) Tp[i] = fexp2(trans[i * S + j] * LOG2E);

        float al = fexp2((bos[j] + gem[j]) * LOG2E);
        int sc = 0;
        for (int t = 1; t < len; ++t) {
            float a0 = __shfl(al, 0), a1 = __shfl(al, 1);
            float a2 = __shfl(al, 2), a3 = __shfl(al, 3);
            float a4 = __shfl(al, 4), a5 = __shfl(al, 5);
            float a6 = __shfl(al, 6), a7 = __shfl(al, 7);
            float acc =      a0 * Tp[0];
            acc = fmaf(a1, Tp[1], acc);  acc = fmaf(a2, Tp[2], acc);
            acc = fmaf(a3, Tp[3], acc);  acc = fmaf(a4, Tp[4], acc);
            acc = fmaf(a5, Tp[5], acc);  acc = fmaf(a6, Tp[6], acc);
            acc = fmaf(a7, Tp[7], acc);
            al = acc * sm[t * 8 + j];
            if ((t & 3) == 0) {          // group renorm every 4 steps
                float m = al;
                m = fmaxf(m, __shfl_xor(m, 1));
                m = fmaxf(m, __shfl_xor(m, 2));
                m = fmaxf(m, __shfl_xor(m, 4));
                const int ex = (int)(__float_as_uint(m) >> 23) - 126;
                sc += ex;
                al = ldexpf(al, -ex);
            }
        }
        float f = al * fexp2(eos[j] * LOG2E);
        f += __shfl_xor(f, 1);
        f += __shfl_xor(f, 2);
        f += __shfl_xor(f, 4);
        if (lane == 0)
            ws[B + b] = flog2(fmaxf(f, 1e-36f)) + (float)sc;  // logZ_den, base 2
    }
}

extern "C" __global__ void crf_finalize(const float* __restrict__ ws,
                                        float* __restrict__ out, int B)
{
    const int tid = threadIdx.x;
    float v = (tid < B) ? (ws[B + tid] - ws[tid]) : 0.0f;
#pragma unroll
    for (int o = 32; o > 0; o >>= 1) v += __shfl_down(v, o, 64);
    if (tid == 0) out[0] = v * (LN2 / (float)B);
}

extern "C" void kernel_launch(void* const* d_in, const int* in_sizes, int n_in,
                              void* d_out, int out_size, void* d_ws, size_t ws_size,
                              hipStream_t stream)
{
    const float* em      = (const float*)d_in[0];
    const float* trans   = (const float*)d_in[1];
    const float* bos     = (const float*)d_in[2];
    const float* eos     = (const float*)d_in[3];
    const int*   lengths = (const int*)d_in[4];
    const int*   targets = (const int*)d_in[5];
    const int*   tlens   = (const int*)d_in[6];
    float* out = (float*)d_out;
    float* ws  = (float*)d_ws;

    const int B  = in_sizes[4];              // 16
    const int SS = in_sizes[1];              // 64
    int S = 1; while (S * S < SS) ++S;       // 8
    const int T = in_sizes[0] / (B * S);     // 2048
    const int L = in_sizes[5] / B;           // 256

    const size_t shmem = (size_t)T * S * sizeof(float);  // 64 KiB

    hipLaunchKernelGGL(crf_fwd, dim3(2 * B), dim3(64), shmem, stream,
                       em, trans, bos, eos, lengths, targets, tlens, ws,
                       B, T, S, L);
    hipLaunchKernelGGL(crf_finalize, dim3(1), dim3(64), 0, stream, ws, out, B);
}

// Round 4
// 286.656 us; speedup vs baseline: 1.8650x; 1.4447x over previous
//
#include <hip/hip_runtime.h>
#include <math.h>

// CTC-CRF NLL: mean_b( logZ_den(b) - logZ_num(b) ), B=16,T=2048,S=8,L=256.
//
// R3: latency-pipelined version of R2 (which passed, absmax 0.0, but ran at
// 412 cy/step from exposed single-wave latency).
//  * Numerator: one wave per batch, 4 lattice positions/lane, prob domain,
//    per-lane block-floating-point. NEW: 4-step groups with
//      - LDS emission reads double-buffered ONE GROUP AHEAD (16 ds_read_b64
//        issued ~160 cy before use),
//      - all scale machinery (renorm, s-shfl, d>50 rebase, fs) at group
//        boundaries only; per-step handoff is one mul by fs0 (lane0: 0),
//      - x8-unrolled main loop (two groups, alternating buffers, no copies).
//  * Denominator: lane j = state j (mirrored x8), grouped loads, fma-tree
//    dot (depth 3), renorm once per 4 steps.
//  * ws: 2B floats.

#define LOG2E 1.4426950408889634f
#define LN2   0.69314718055994531f

__device__ __forceinline__ float fexp2(float x) {
#if __has_builtin(__builtin_amdgcn_exp2f)
    return __builtin_amdgcn_exp2f(x);
#else
    return exp2f(x);
#endif
}
__device__ __forceinline__ float flog2(float x) {
#if __has_builtin(__builtin_amdgcn_logf)
    return __builtin_amdgcn_logf(x);
#else
    return __log2f(x);
#endif
}
__device__ __forceinline__ float lse2(float a, float b) {   // log2(2^a+2^b)
    float m = fmaxf(a, b);
    float d = fminf(a, b) - m;
    return m + flog2(1.0f + fexp2(d));
}

struct NumC { float tee[4], txe[4], tex[4], txx[4]; };

__device__ __forceinline__ void num_step(const float2* p, float* E, float* X,
                                         float fs0, const NumC& c) {
    // boundary value = neighbor's E[3]/X[3] after the previous step
    float bE = __shfl_up(E[3], 1);
    float bX = __shfl_up(X[3], 1);
    float inE = bE * fs0;                    // fs0 = 2^(bs-s), 0 on lane 0
    float inX = bX * fs0;
    float nE0 = p[0].x * fmaf(inE,  c.tee[0], inX  * c.txe[0]);
    float nE1 = p[1].x * fmaf(E[0], c.tee[1], X[0] * c.txe[1]);
    float nE2 = p[2].x * fmaf(E[1], c.tee[2], X[1] * c.txe[2]);
    float nE3 = p[3].x * fmaf(E[2], c.tee[3], X[2] * c.txe[3]);
    float nX0 = p[0].y * fmaf(E[0], c.tex[0], X[0] * c.txx[0]);
    float nX1 = p[1].y * fmaf(E[1], c.tex[1], X[1] * c.txx[1]);
    float nX2 = p[2].y * fmaf(E[2], c.tex[2], X[2] * c.txx[2]);
    float nX3 = p[3].y * fmaf(E[3], c.tex[3], X[3] * c.txx[3]);
    E[0] = nE0; E[1] = nE1; E[2] = nE2; E[3] = nE3;
    X[0] = nX0; X[1] = nX1; X[2] = nX2; X[3] = nX3;
}

__device__ __forceinline__ void num_boundary(float* E, float* X, int& s,
                                             float& fs0, int lane) {
    float m = fmaxf(fmaxf(fmaxf(E[0], E[1]), fmaxf(E[2], E[3])),
                    fmaxf(fmaxf(X[0], X[1]), fmaxf(X[2], X[3])));
    const bool live = (m > 0.0f);
    const int ex = live ? ((int)(__float_as_uint(m) >> 23) - 126) : 0;
    s += ex;
    const float sc = ldexpf(1.0f, -ex);      // 1 if dead
#pragma unroll
    for (int k = 0; k < 4; ++k) { E[k] *= sc; X[k] *= sc; }
    const int bs = __shfl_up(s, 1);
    if (!live) s = bs;                       // dead lane adopts neighbor scale
    int d = bs - s;
    if (d > 50) {                            // incoming dwarfs us: rebase (rare)
        const float f = ldexpf(1.0f, -d);    // may flush to 0: negligible mass
#pragma unroll
        for (int k = 0; k < 4; ++k) { E[k] *= f; X[k] *= f; }
        s = bs; d = 0;
    }
    fs0 = (lane == 0) ? 0.0f : ldexpf(1.0f, d);  // d<=50: never inf
}

__device__ __forceinline__ void load_group(const float2* sm2, int t0, int len,
                                           const int* e, float2 g[4][4]) {
#pragma unroll
    for (int q = 0; q < 4; ++q) {
        int t = t0 + q; if (t >= len) t = len - 1;   // clamped: always valid
#pragma unroll
        for (int k = 0; k < 4; ++k) g[q][k] = sm2[t * 4 + e[k]];
    }
}

__device__ __forceinline__ float den_step(float al, float emt, const float* Tp) {
    float a0 = __shfl(al, 0), a1 = __shfl(al, 1);
    float a2 = __shfl(al, 2), a3 = __shfl(al, 3);
    float a4 = __shfl(al, 4), a5 = __shfl(al, 5);
    float a6 = __shfl(al, 6), a7 = __shfl(al, 7);
    float q0 = fmaf(a1, Tp[1], a0 * Tp[0]);   // depth-3 tree, not 8-deep chain
    float q1 = fmaf(a3, Tp[3], a2 * Tp[2]);
    float q2 = fmaf(a5, Tp[5], a4 * Tp[4]);
    float q3 = fmaf(a7, Tp[7], a6 * Tp[6]);
    return ((q0 + q1) + (q2 + q3)) * emt;
}

extern "C" __global__ void __launch_bounds__(64)
crf_fwd(const float* __restrict__ em, const float* __restrict__ trans,
        const float* __restrict__ bos, const float* __restrict__ eos,
        const int* __restrict__ lengths, const int* __restrict__ targets,
        const int* __restrict__ tlens, float* __restrict__ ws,
        int B, int T, int S, int L)
{
    extern __shared__ float sm[];
    const int bid  = blockIdx.x;
    const int lane = threadIdx.x;            // one wave per block
    const int half = S >> 1;                 // = 4
    const bool is_den = (bid >= B);
    const int b = is_den ? (bid - B) : bid;
    const float* gem = em + (size_t)b * T * S;
    const int len = lengths[b];

    if (!is_den) {
        // ======================= NUMERATOR =======================
        // sm2[t*4+j] = (2^em[t][j], 2^em[t][j+4]) interleaved pairs.
        for (int t = lane; t < T; t += 64) {
            const float4* gr = (const float4*)(gem + t * S);
            float4 a = gr[0], c4 = gr[1];
            float4 w0, w1;
            w0.x = fexp2(a.x * LOG2E); w0.y = fexp2(c4.x * LOG2E);
            w0.z = fexp2(a.y * LOG2E); w0.w = fexp2(c4.y * LOG2E);
            w1.x = fexp2(a.z * LOG2E); w1.y = fexp2(c4.z * LOG2E);
            w1.z = fexp2(a.w * LOG2E); w1.w = fexp2(c4.w * LOG2E);
            ((float4*)sm)[t * 2]     = w0;
            ((float4*)sm)[t * 2 + 1] = w1;
        }
        __syncthreads();
        const float2* sm2 = (const float2*)sm;

        const int u0 = lane * 4;
        int e[4], ep[4];
        {
            const int base = b * L;
#pragma unroll
            for (int k = 0; k < 4; ++k) {
                int u = u0 + k;
                e[k] = targets[base + ((u < L) ? u : (L - 1))];
            }
            ep[0] = (u0 > 0) ? targets[base + u0 - 1] : e[0];
            ep[1] = e[0]; ep[2] = e[1]; ep[3] = e[2];
        }
        NumC c;
#pragma unroll
        for (int k = 0; k < 4; ++k) {
            c.tee[k] = fexp2(trans[ep[k] * S + e[k]] * LOG2E);
            c.txe[k] = fexp2(trans[(ep[k] + half) * S + e[k]] * LOG2E);
            c.tex[k] = fexp2(trans[e[k] * S + e[k] + half] * LOG2E);
            c.txx[k] = fexp2(trans[(e[k] + half) * S + e[k] + half] * LOG2E);
        }

        float E[4] = {0.f, 0.f, 0.f, 0.f}, X[4] = {0.f, 0.f, 0.f, 0.f};
        int s = 0;
        if (lane == 0) E[0] = fexp2((bos[e[0]] + gem[e[0]]) * LOG2E);

        float2 A[4][4], Bf[4][4];
        int t0 = 1;
        load_group(sm2, t0, len, e, A);
        float fs0 = (lane == 0) ? 0.0f : 1.0f;

        while (t0 + 7 < len) {               // two full groups per iteration
            load_group(sm2, t0 + 4, len, e, Bf);
#pragma unroll
            for (int q = 0; q < 4; ++q) num_step(A[q], E, X, fs0, c);
            num_boundary(E, X, s, fs0, lane);
            load_group(sm2, t0 + 8, len, e, A);
#pragma unroll
            for (int q = 0; q < 4; ++q) num_step(Bf[q], E, X, fs0, c);
            num_boundary(E, X, s, fs0, lane);
            t0 += 8;
        }
        // tail: up to 2 guarded groups; current buffer is A
#pragma unroll 1
        for (int g = 0; g < 2; ++g) {
            if (t0 < len) {
#pragma unroll
                for (int q = 0; q < 4; ++q)
                    if (t0 + q < len) num_step(A[q], E, X, fs0, c);
                num_boundary(E, X, s, fs0, lane);
                t0 += 4;
                load_group(sm2, t0, len, e, A);   // clamped, always safe
            }
        }

        const int uf = tlens[b] - 1;
        if (lane == (uf >> 2)) {
            const int k = uf & 3;
            const float fE = (k == 0) ? E[0] : (k == 1) ? E[1] : (k == 2) ? E[2] : E[3];
            const float fX = (k == 0) ? X[0] : (k == 1) ? X[1] : (k == 2) ? X[2] : X[3];
            const int  ek = (k == 0) ? e[0] : (k == 1) ? e[1] : (k == 2) ? e[2] : e[3];
            const float le = (fE > 1e-36f)
                ? flog2(fE) + (float)s + eos[ek] * LOG2E : -3.0e38f;
            const float lx = (fX > 1e-36f)
                ? flog2(fX) + (float)s + eos[ek + half] * LOG2E : -3.0e38f;
            ws[b] = lse2(le, lx);            // logZ_num, base 2
        }
    } else {
        // ======================= DENOMINATOR =======================
        for (int idx = lane; idx < T * 2; idx += 64) {   // float4 granules
            float4 v = ((const float4*)gem)[idx];
            float4 w;
            w.x = fexp2(v.x * LOG2E); w.y = fexp2(v.y * LOG2E);
            w.z = fexp2(v.z * LOG2E); w.w = fexp2(v.w * LOG2E);
            ((float4*)sm)[idx] = w;
        }
        __syncthreads();

        const int j = lane & (S - 1);        // mirrored x8; shfl reads lanes 0-7
        float Tp[8];
#pragma unroll
        for (int i = 0; i < 8; ++i) Tp[i] = fexp2(trans[i * S + j] * LOG2E);

        float al = fexp2((bos[j] + gem[j]) * LOG2E);
        int sc = 0;
        int t = 1;
        while (t + 3 < len) {
            float m0 = sm[t * 8 + j];
            float m1 = sm[(t + 1) * 8 + j];
            float m2 = sm[(t + 2) * 8 + j];
            float m3 = sm[(t + 3) * 8 + j];
            al = den_step(al, m0, Tp);
            al = den_step(al, m1, Tp);
            al = den_step(al, m2, Tp);
            al = den_step(al, m3, Tp);
            float mm = al;                   // group renorm (al > 0 always)
            mm = fmaxf(mm, __shfl_xor(mm, 1));
            mm = fmaxf(mm, __shfl_xor(mm, 2));
            mm = fmaxf(mm, __shfl_xor(mm, 4));
            const int ex = (int)(__float_as_uint(mm) >> 23) - 126;
            sc += ex;
            al = ldexpf(al, -ex);
            t += 4;
        }
        while (t < len) { al = den_step(al, sm[t * 8 + j], Tp); ++t; }

        float f = al * fexp2(eos[j] * LOG2E);
        f += __shfl_xor(f, 1);
        f += __shfl_xor(f, 2);
        f += __shfl_xor(f, 4);
        if (lane == 0)
            ws[B + b] = flog2(fmaxf(f, 1e-36f)) + (float)sc;  // logZ_den, base 2
    }
}

extern "C" __global__ void crf_finalize(const float* __restrict__ ws,
                                        float* __restrict__ out, int B)
{
    const int tid = threadIdx.x;
    float v = (tid < B) ? (ws[B + tid] - ws[tid]) : 0.0f;
#pragma unroll
    for (int o = 32; o > 0; o >>= 1) v += __shfl_down(v, o, 64);
    if (tid == 0) out[0] = v * (LN2 / (float)B);
}

extern "C" void kernel_launch(void* const* d_in, const int* in_sizes, int n_in,
                              void* d_out, int out_size, void* d_ws, size_t ws_size,
                              hipStream_t stream)
{
    const float* em      = (const float*)d_in[0];
    const float* trans   = (const float*)d_in[1];
    const float* bos     = (const float*)d_in[2];
    const float* eos     = (const float*)d_in[3];
    const int*   lengths = (const int*)d_in[4];
    const int*   targets = (const int*)d_in[5];
    const int*   tlens   = (const int*)d_in[6];
    float* out = (float*)d_out;
    float* ws  = (float*)d_ws;

    const int B  = in_sizes[4];              // 16
    const int SS = in_sizes[1];              // 64
    int S = 1; while (S * S < SS) ++S;       // 8
    const int T = in_sizes[0] / (B * S);     // 2048
    const int L = in_sizes[5] / B;           // 256

    const size_t shmem = (size_t)T * S * sizeof(float);  // 64 KiB

    hipLaunchKernelGGL(crf_fwd, dim3(2 * B), dim3(64), shmem, stream,
                       em, trans, bos, eos, lengths, targets, tlens, ws,
                       B, T, S, L);
    hipLaunchKernelGGL(crf_finalize, dim3(1), dim3(64), 0, stream, ws, out, B);
}

// Round 5
// 252.546 us; speedup vs baseline: 2.1169x; 1.1351x over previous
//
#include <hip/hip_runtime.h>
#include <math.h>

// CTC-CRF NLL: mean_b( logZ_den(b) - logZ_num(b) ), B=16,T=2048,S=8,L=256.
//
// R4: all cross-lane exchange via DPP (pure VALU, ~4cy) instead of
// __shfl/ds_bpermute (lgkmcnt, ~100cy, and in-order DS retire was draining
// the ds_read prefetch every step in R3).
//  * Numerator: one wave/batch, 4 positions/lane, prob domain, per-lane
//    block-floating-point. Neighbor handoff: row_shr:1 + row_bcast15 +
//    cndmask ((lane&15)==0). Lane 0 inflow is 0 via DPP bound_ctrl.
//    Scale machinery every 8 steps; fs0 pre-folded into tee0/txe0.
//    Emissions pre-exp2'd in LDS; ds_read_b64 x16 prefetched a group ahead
//    (lgkm now holds ONLY these reads -> fine-grained waits work).
//  * Denominator: lane j = state j mirrored x8 across the wave; 8x8 matvec
//    per step via 7 row_ror DPPs + fma tree (per-lane coeff T[(j-r)&7][j]).
//    Renorm every 4 via DPP-ror max folding.

#define LOG2E 1.4426950408889634f
#define LN2   0.69314718055994531f

#define CTL_SHR1  0x111
#define CTL_ROR(r) (0x120 + (r))
#define CTL_BC15  0x142

#if __has_builtin(__builtin_amdgcn_update_dpp)
template <int CTRL>
__device__ __forceinline__ float fdpp(float x) {
    return __int_as_float(__builtin_amdgcn_update_dpp(
        0, __float_as_int(x), CTRL, 0xF, 0xF, true));
}
template <int CTRL>
__device__ __forceinline__ int idpp(int x) {
    return __builtin_amdgcn_update_dpp(0, x, CTRL, 0xF, 0xF, true);
}
#else
// Fallback (slow but correct): emulate the three DPP patterns with shfl.
template <int CTRL>
__device__ __forceinline__ float fdpp(float x) {
    const int lane = threadIdx.x & 63;
    if (CTRL == CTL_SHR1) {
        float v = __shfl_up(x, 1, 16);
        return ((lane & 15) == 0) ? 0.0f : v;
    } else if (CTRL == CTL_BC15) {
        int src = ((lane & ~15) - 1) & 63;
        float v = __shfl(x, src, 64);
        return (lane < 16) ? 0.0f : v;
    } else {  // ROW_ROR(r), r = CTRL - 0x120
        const int r = CTRL - 0x120;
        int src = (lane & ~15) | ((lane - r) & 15);
        return __shfl(x, src, 64);
    }
}
template <int CTRL>
__device__ __forceinline__ int idpp(int x) {
    return __float_as_int(fdpp<CTRL>(__int_as_float(x)));
}
#endif

__device__ __forceinline__ float fexp2(float x) {
#if __has_builtin(__builtin_amdgcn_exp2f)
    return __builtin_amdgcn_exp2f(x);
#else
    return exp2f(x);
#endif
}
__device__ __forceinline__ float flog2(float x) {
#if __has_builtin(__builtin_amdgcn_logf)
    return __builtin_amdgcn_logf(x);
#else
    return __log2f(x);
#endif
}
__device__ __forceinline__ float lse2(float a, float b) {   // log2(2^a+2^b)
    float m = fmaxf(a, b);
    float d = fminf(a, b) - m;
    return m + flog2(1.0f + fexp2(d));
}

struct NumC { float tee[4], txe[4], tex[4], txx[4]; };

// One time step. Inflow from lane-1 (previous step's E[3]/X[3]) via DPP:
// row_shr:1 within rows, row_bcast15 across row boundaries, selected by rs.
// teeF/txeF carry the cross-lane scale factor fs0 (0 on lane 0 handled by
// DPP returning 0 for lane 0 + fs0 forced 0).
__device__ __forceinline__ void num_step(const float2* p, float* E, float* X,
                                         float teeF, float txeF, bool rs,
                                         const NumC& c) {
    float sE = fdpp<CTL_SHR1>(E[3]);
    float bE = fdpp<CTL_BC15>(E[3]);
    float sX = fdpp<CTL_SHR1>(X[3]);
    float bX = fdpp<CTL_BC15>(X[3]);
    float nbE = rs ? bE : sE;
    float nbX = rs ? bX : sX;
    float nE0 = p[0].x * fmaf(nbE,  teeF,     nbX  * txeF);
    float nE1 = p[1].x * fmaf(E[0], c.tee[1], X[0] * c.txe[1]);
    float nE2 = p[2].x * fmaf(E[1], c.tee[2], X[1] * c.txe[2]);
    float nE3 = p[3].x * fmaf(E[2], c.tee[3], X[2] * c.txe[3]);
    float nX0 = p[0].y * fmaf(E[0], c.tex[0], X[0] * c.txx[0]);
    float nX1 = p[1].y * fmaf(E[1], c.tex[1], X[1] * c.txx[1]);
    float nX2 = p[2].y * fmaf(E[2], c.tex[2], X[2] * c.txx[2]);
    float nX3 = p[3].y * fmaf(E[3], c.tex[3], X[3] * c.txx[3]);
    E[0] = nE0; E[1] = nE1; E[2] = nE2; E[3] = nE3;
    X[0] = nX0; X[1] = nX1; X[2] = nX2; X[3] = nX3;
}

// Every-8-steps scale maintenance: per-lane renorm, neighbor-scale exchange
// (DPP on int s), rebase if incoming scale dwarfs ours (d>30), fold fs0
// into the inflow coefficients.
__device__ __forceinline__ void num_boundary(float* E, float* X, int& s,
                                             float& teeF, float& txeF,
                                             bool rs, int lane, const NumC& c) {
    float m = fmaxf(fmaxf(fmaxf(E[0], E[1]), fmaxf(E[2], E[3])),
                    fmaxf(fmaxf(X[0], X[1]), fmaxf(X[2], X[3])));
    const bool live = (m > 0.0f);
    const int ex = live ? ((int)(__float_as_uint(m) >> 23) - 126) : 0;
    s += ex;
    const int ss = idpp<CTL_SHR1>(s);
    const int bb = idpp<CTL_BC15>(s);
    const int bs = rs ? bb : ss;     // post-renorm neighbor scale (0 on lane 0)
    if (!live) s = bs;               // dead lane adopts neighbor scale
    int d = (lane == 0) ? 0 : (bs - s);
    const int extra = (d > 30) ? d : 0;   // incoming dwarfs us: adopt, flush
    s += extra;
    d -= extra;
    const float fsc = ldexpf(1.0f, -(ex + extra));
#pragma unroll
    for (int k = 0; k < 4; ++k) { E[k] *= fsc; X[k] *= fsc; }
    const float fs0 = (lane == 0) ? 0.0f : ldexpf(1.0f, d);  // d<=30: finite
    teeF = c.tee[0] * fs0;
    txeF = c.txe[0] * fs0;
}

__device__ __forceinline__ void load_group(const float2* sm2, int t0, int len,
                                           const int* e, float2 g[4][4]) {
#pragma unroll
    for (int q = 0; q < 4; ++q) {
        int t = t0 + q; if (t >= len) t = len - 1;   // clamped: always valid
#pragma unroll
        for (int k = 0; k < 4; ++k) g[q][k] = sm2[t * 4 + e[k]];
    }
}

// Denominator step: alpha'_j = (sum_i alpha_i T[i][j]) * em_j, where the
// rotated alpha_{(j-r)&7} arrives via row_ror:r (alpha mirrored x8/wave).
__device__ __forceinline__ float den_step(float al, float emt, const float* Tr) {
    float v1 = fdpp<CTL_ROR(1)>(al);
    float v2 = fdpp<CTL_ROR(2)>(al);
    float v3 = fdpp<CTL_ROR(3)>(al);
    float v4 = fdpp<CTL_ROR(4)>(al);
    float v5 = fdpp<CTL_ROR(5)>(al);
    float v6 = fdpp<CTL_ROR(6)>(al);
    float v7 = fdpp<CTL_ROR(7)>(al);
    float q0 = fmaf(v1, Tr[1], al * Tr[0]);
    float q1 = fmaf(v3, Tr[3], v2 * Tr[2]);
    float q2 = fmaf(v5, Tr[5], v4 * Tr[4]);
    float q3 = fmaf(v7, Tr[7], v6 * Tr[6]);
    return ((q0 + q1) + (q2 + q3)) * emt;
}

extern "C" __global__ void __launch_bounds__(64)
crf_fwd(const float* __restrict__ em, const float* __restrict__ trans,
        const float* __restrict__ bos, const float* __restrict__ eos,
        const int* __restrict__ lengths, const int* __restrict__ targets,
        const int* __restrict__ tlens, float* __restrict__ ws,
        int B, int T, int S, int L)
{
    extern __shared__ float sm[];
    const int bid  = blockIdx.x;
    const int lane = threadIdx.x;            // one wave per block
    const int half = S >> 1;                 // = 4
    const bool is_den = (bid >= B);
    const int b = is_den ? (bid - B) : bid;
    const float* gem = em + (size_t)b * T * S;
    const int len = lengths[b];
    const bool rs = ((lane & 15) == 0);      // row-start lanes (DPP seam)

    if (!is_den) {
        // ======================= NUMERATOR =======================
        // sm2[t*4+j] = (2^em[t][j], 2^em[t][j+4]) interleaved pairs.
        for (int t = lane; t < T; t += 64) {
            const float4* gr = (const float4*)(gem + t * S);
            float4 a = gr[0], c4 = gr[1];
            float4 w0, w1;
            w0.x = fexp2(a.x * LOG2E); w0.y = fexp2(c4.x * LOG2E);
            w0.z = fexp2(a.y * LOG2E); w0.w = fexp2(c4.y * LOG2E);
            w1.x = fexp2(a.z * LOG2E); w1.y = fexp2(c4.z * LOG2E);
            w1.z = fexp2(a.w * LOG2E); w1.w = fexp2(c4.w * LOG2E);
            ((float4*)sm)[t * 2]     = w0;
            ((float4*)sm)[t * 2 + 1] = w1;
        }
        __syncthreads();
        const float2* sm2 = (const float2*)sm;

        const int u0 = lane * 4;
        int e[4], ep[4];
        {
            const int base = b * L;
#pragma unroll
            for (int k = 0; k < 4; ++k) {
                int u = u0 + k;
                e[k] = targets[base + ((u < L) ? u : (L - 1))];
            }
            ep[0] = (u0 > 0) ? targets[base + u0 - 1] : e[0];
            ep[1] = e[0]; ep[2] = e[1]; ep[3] = e[2];
        }
        NumC c;
#pragma unroll
        for (int k = 0; k < 4; ++k) {
            c.tee[k] = fexp2(trans[ep[k] * S + e[k]] * LOG2E);
            c.txe[k] = fexp2(trans[(ep[k] + half) * S + e[k]] * LOG2E);
            c.tex[k] = fexp2(trans[e[k] * S + e[k] + half] * LOG2E);
            c.txx[k] = fexp2(trans[(e[k] + half) * S + e[k] + half] * LOG2E);
        }

        float E[4] = {0.f, 0.f, 0.f, 0.f}, X[4] = {0.f, 0.f, 0.f, 0.f};
        int s = 0;
        if (lane == 0) E[0] = fexp2((bos[e[0]] + gem[e[0]]) * LOG2E);
        float teeF = c.tee[0], txeF = c.txe[0];   // fs0 = 1 initially
        if (lane == 0) { teeF = 0.0f; txeF = 0.0f; }

        float2 A[4][4], Bf[4][4];
        int t0 = 1;
        load_group(sm2, t0, len, e, A);

        while (t0 + 7 < len) {                // 8 steps + 1 boundary per iter
            load_group(sm2, t0 + 4, len, e, Bf);
#pragma unroll
            for (int q = 0; q < 4; ++q) num_step(A[q], E, X, teeF, txeF, rs, c);
            load_group(sm2, t0 + 8, len, e, A);
#pragma unroll
            for (int q = 0; q < 4; ++q) num_step(Bf[q], E, X, teeF, txeF, rs, c);
            num_boundary(E, X, s, teeF, txeF, rs, lane, c);
            t0 += 8;
        }
        while (t0 < len) {                    // tail < 8 steps
            float2 p[4];
#pragma unroll
            for (int k = 0; k < 4; ++k) p[k] = sm2[t0 * 4 + e[k]];
            num_step(p, E, X, teeF, txeF, rs, c);
            ++t0;
        }

        const int uf = tlens[b] - 1;
        if (lane == (uf >> 2)) {
            const int k = uf & 3;
            const float fE = (k == 0) ? E[0] : (k == 1) ? E[1] : (k == 2) ? E[2] : E[3];
            const float fX = (k == 0) ? X[0] : (k == 1) ? X[1] : (k == 2) ? X[2] : X[3];
            const int  ek = (k == 0) ? e[0] : (k == 1) ? e[1] : (k == 2) ? e[2] : e[3];
            const float le = (fE > 0.0f)
                ? flog2(fE) + (float)s + eos[ek] * LOG2E : -3.0e38f;
            const float lx = (fX > 0.0f)
                ? flog2(fX) + (float)s + eos[ek + half] * LOG2E : -3.0e38f;
            ws[b] = lse2(le, lx);            // logZ_num, base 2
        }
    } else {
        // ======================= DENOMINATOR =======================
        for (int idx = lane; idx < T * 2; idx += 64) {   // float4 granules
            float4 v = ((const float4*)gem)[idx];
            float4 w;
            w.x = fexp2(v.x * LOG2E); w.y = fexp2(v.y * LOG2E);
            w.z = fexp2(v.z * LOG2E); w.w = fexp2(v.w * LOG2E);
            ((float4*)sm)[idx] = w;
        }
        __syncthreads();

        const int j = lane & (S - 1);        // mirrored x8 across the wave
        float Tr[8];
#pragma unroll
        for (int r = 0; r < 8; ++r)
            Tr[r] = fexp2(trans[((j - r) & 7) * S + j] * LOG2E);

        float al = fexp2((bos[j] + gem[j]) * LOG2E);
        int sc = 0;
        int t = 1;
        float c0 = sm[8 + j];                // prefetch t=1..4 (len >= 1)
        float c1 = sm[((2 < len) ? 2 : (len - 1)) * 8 + j];
        float c2 = sm[((3 < len) ? 3 : (len - 1)) * 8 + j];
        float c3 = sm[((4 < len) ? 4 : (len - 1)) * 8 + j];
        while (t + 3 < len) {
            const int t4 = t + 4;
            float n0 = sm[(((t4)     < len) ? (t4)     : (len - 1)) * 8 + j];
            float n1 = sm[(((t4 + 1) < len) ? (t4 + 1) : (len - 1)) * 8 + j];
            float n2 = sm[(((t4 + 2) < len) ? (t4 + 2) : (len - 1)) * 8 + j];
            float n3 = sm[(((t4 + 3) < len) ? (t4 + 3) : (len - 1)) * 8 + j];
            al = den_step(al, c0, Tr);
            al = den_step(al, c1, Tr);
            al = den_step(al, c2, Tr);
            al = den_step(al, c3, Tr);
            float mm = fmaxf(al, fdpp<CTL_ROR(4)>(al));   // renorm every 4
            mm = fmaxf(mm, fdpp<CTL_ROR(2)>(mm));
            mm = fmaxf(mm, fdpp<CTL_ROR(1)>(mm));
            const int ex = (int)(__float_as_uint(mm) >> 23) - 126;
            sc += ex;
            al = ldexpf(al, -ex);
            c0 = n0; c1 = n1; c2 = n2; c3 = n3;
            t += 4;
        }
        while (t < len) { al = den_step(al, sm[t * 8 + j], Tr); ++t; }

        float f = al * fexp2(eos[j] * LOG2E);
        f += fdpp<CTL_ROR(4)>(f);
        f += fdpp<CTL_ROR(2)>(f);
        f += fdpp<CTL_ROR(1)>(f);
        if (lane == 0)
            ws[B + b] = flog2(fmaxf(f, 1e-36f)) + (float)sc;  // logZ_den, base2
    }
}

extern "C" __global__ void crf_finalize(const float* __restrict__ ws,
                                        float* __restrict__ out, int B)
{
    const int tid = threadIdx.x;
    float v = (tid < B) ? (ws[B + tid] - ws[tid]) : 0.0f;
#pragma unroll
    for (int o = 32; o > 0; o >>= 1) v += __shfl_down(v, o, 64);
    if (tid == 0) out[0] = v * (LN2 / (float)B);
}

extern "C" void kernel_launch(void* const* d_in, const int* in_sizes, int n_in,
                              void* d_out, int out_size, void* d_ws, size_t ws_size,
                              hipStream_t stream)
{
    const float* em      = (const float*)d_in[0];
    const float* trans   = (const float*)d_in[1];
    const float* bos     = (const float*)d_in[2];
    const float* eos     = (const float*)d_in[3];
    const int*   lengths = (const int*)d_in[4];
    const int*   targets = (const int*)d_in[5];
    const int*   tlens   = (const int*)d_in[6];
    float* out = (float*)d_out;
    float* ws  = (float*)d_ws;

    const int B  = in_sizes[4];              // 16
    const int SS = in_sizes[1];              // 64
    int S = 1; while (S * S < SS) ++S;       // 8
    const int T = in_sizes[0] / (B * S);     // 2048
    const int L = in_sizes[5] / B;           // 256

    const size_t shmem = (size_t)T * S * sizeof(float);  // 64 KiB

    hipLaunchKernelGGL(crf_fwd, dim3(2 * B), dim3(64), shmem, stream,
                       em, trans, bos, eos, lengths, targets, tlens, ws,
                       B, T, S, L);
    hipLaunchKernelGGL(crf_finalize, dim3(1), dim3(64), 0, stream, ws, out, B);
}

// Round 8
// 243.386 us; speedup vs baseline: 2.1966x; 1.0376x over previous
//
#include <hip/hip_runtime.h>
#include <math.h>

// CTC-CRF NLL: mean_b( logZ_den(b) - logZ_num(b) ), B=16,T=2048,S=8,L=256.
//
// R7 = R6 with the raw-offset asm ds_read replaced by C-level LDS loads
// pinned with compiler memory fences (asm volatile "" ::: "memory").
// R6's moderate error (432) is attributed to the asm reads assuming the
// dynamic-LDS base is byte 0; C-level loads use compiler addressing and
// cannot be inconsistent. The fence prevents the R4 sink-to-use pathology
// (loads must issue before the fence; waits stay fine-grained before use).
//
// Single fused kernel, 16 blocks x 128 threads:
//  * wave0 = numerator: 4 lattice positions/lane, prob domain, per-lane
//    block floating point, DPP wave_shr:1 handoff (lane0 -> 0 via old=0),
//    4-step groups double-buffered one group ahead, renorm every 8.
//  * wave1 = denominator: lane j = state j mirrored x8; 8x8 matvec/step via
//    7 row_ror DPPs + fma tree; renorm every 4. Runs on a different SIMD.
//  * Epilogue: atomic ticket (counter ws[2B], zeroed by hipMemsetAsync);
//    last block computes the mean. One kernel launch total.

#define LOG2E 1.4426950408889634f
#define LN2   0.69314718055994531f
#define CTL_WSHR1  0x138            // DPP wave_shr:1
#define CTL_ROR(r) (0x120 + (r))    // DPP row_ror:r

template <int CTRL>
__device__ __forceinline__ float fdpp(float x) {
    return __int_as_float(__builtin_amdgcn_update_dpp(
        0, __float_as_int(x), CTRL, 0xF, 0xF, true));
}
template <int CTRL>
__device__ __forceinline__ int idpp(int x) {
    return __builtin_amdgcn_update_dpp(0, x, CTRL, 0xF, 0xF, true);
}

__device__ __forceinline__ void cfence() {   // compiler-level memory fence
    asm volatile("" ::: "memory");
}

__device__ __forceinline__ float fexp2(float x) {
#if __has_builtin(__builtin_amdgcn_exp2f)
    return __builtin_amdgcn_exp2f(x);
#else
    return exp2f(x);
#endif
}
__device__ __forceinline__ float flog2(float x) {
#if __has_builtin(__builtin_amdgcn_logf)
    return __builtin_amdgcn_logf(x);
#else
    return __log2f(x);
#endif
}
__device__ __forceinline__ float lse2(float a, float b) {   // log2(2^a+2^b)
    float m = fmaxf(a, b);
    float d = fminf(a, b) - m;
    return m + flog2(1.0f + fexp2(d));
}

struct NumC { float tee[4], txe[4], tex[4], txx[4]; };

__device__ __forceinline__ void num_step(const float2* p, float* E, float* X,
                                         float teeF, float txeF, const NumC& c) {
    float nbE = fdpp<CTL_WSHR1>(E[3]);   // lane-1's E[3]; lane0 -> 0 (old=0)
    float nbX = fdpp<CTL_WSHR1>(X[3]);
    float nE0 = p[0].x * fmaf(nbE,  teeF,     nbX  * txeF);
    float nE1 = p[1].x * fmaf(E[0], c.tee[1], X[0] * c.txe[1]);
    float nE2 = p[2].x * fmaf(E[1], c.tee[2], X[1] * c.txe[2]);
    float nE3 = p[3].x * fmaf(E[2], c.tee[3], X[2] * c.txe[3]);
    float nX0 = p[0].y * fmaf(E[0], c.tex[0], X[0] * c.txx[0]);
    float nX1 = p[1].y * fmaf(E[1], c.tex[1], X[1] * c.txx[1]);
    float nX2 = p[2].y * fmaf(E[2], c.tex[2], X[2] * c.txx[2]);
    float nX3 = p[3].y * fmaf(E[3], c.tex[3], X[3] * c.txx[3]);
    E[0] = nE0; E[1] = nE1; E[2] = nE2; E[3] = nE3;
    X[0] = nX0; X[1] = nX1; X[2] = nX2; X[3] = nX3;
}

__device__ __forceinline__ void num_boundary(float* E, float* X, int& s,
                                             float& teeF, float& txeF,
                                             int lane, const NumC& c) {
    float m = fmaxf(fmaxf(fmaxf(E[0], E[1]), fmaxf(E[2], E[3])),
                    fmaxf(fmaxf(X[0], X[1]), fmaxf(X[2], X[3])));
    const bool live = (m > 0.0f);
    const int ex = live ? ((int)(__float_as_uint(m) >> 23) - 126) : 0;
    s += ex;
    const int bs = idpp<CTL_WSHR1>(s);       // neighbor scale (lane0 -> 0)
    if (!live) s = bs;                       // dead lane adopts neighbor scale
    int d = (lane == 0) ? 0 : (bs - s);
    const int extra = (d > 30) ? d : 0;      // incoming dwarfs us: adopt, flush
    s += extra; d -= extra;
    const float fsc = ldexpf(1.0f, -(ex + extra));
#pragma unroll
    for (int k = 0; k < 4; ++k) { E[k] *= fsc; X[k] *= fsc; }
    const float fs0 = (lane == 0) ? 0.0f : ldexpf(1.0f, d);  // d<=30: finite
    teeF = c.tee[0] * fs0;
    txeF = c.txe[0] * fs0;
}

__device__ __forceinline__ float den_step(float al, float emt, const float* Tr) {
    float v1 = fdpp<CTL_ROR(1)>(al);
    float v2 = fdpp<CTL_ROR(2)>(al);
    float v3 = fdpp<CTL_ROR(3)>(al);
    float v4 = fdpp<CTL_ROR(4)>(al);
    float v5 = fdpp<CTL_ROR(5)>(al);
    float v6 = fdpp<CTL_ROR(6)>(al);
    float v7 = fdpp<CTL_ROR(7)>(al);
    float q0 = fmaf(v1, Tr[1], al * Tr[0]);
    float q1 = fmaf(v3, Tr[3], v2 * Tr[2]);
    float q2 = fmaf(v5, Tr[5], v4 * Tr[4]);
    float q3 = fmaf(v7, Tr[7], v6 * Tr[6]);
    return ((q0 + q1) + (q2 + q3)) * emt;
}

extern "C" __global__ void __launch_bounds__(128)
crf_fused(const float* __restrict__ em, const float* __restrict__ trans,
          const float* __restrict__ bos, const float* __restrict__ eos,
          const int* __restrict__ lengths, const int* __restrict__ targets,
          const int* __restrict__ tlens,
          float* __restrict__ ws, float* __restrict__ out,
          int B, int T, int S, int L)
{
    extern __shared__ float sm[];
    const int b    = blockIdx.x;
    const int tid  = threadIdx.x;
    const int half = S >> 1;                 // = 4
    const float* gem = em + (size_t)b * T * S;
    const int len = lengths[b];

    // ---- stage emissions once, interleaved base-2 probs:
    // floats t*8 + 2j   = 2^em[t][j]   (enter j),  j in [0,4)
    //        t*8 + 2j+1 = 2^em[t][j+4] (extend j+4)
    for (int t = tid; t < T; t += 128) {
        const float4* gr = (const float4*)(gem + t * S);
        float4 a = gr[0], c4 = gr[1];
        float4 w0, w1;
        w0.x = fexp2(a.x * LOG2E); w0.y = fexp2(c4.x * LOG2E);
        w0.z = fexp2(a.y * LOG2E); w0.w = fexp2(c4.y * LOG2E);
        w1.x = fexp2(a.z * LOG2E); w1.y = fexp2(c4.z * LOG2E);
        w1.z = fexp2(a.w * LOG2E); w1.w = fexp2(c4.w * LOG2E);
        ((float4*)sm)[t * 2]     = w0;
        ((float4*)sm)[t * 2 + 1] = w1;
    }
    __syncthreads();

    const int wv   = tid >> 6;
    const int lane = tid & 63;

    if (wv == 0) {
        // ======================= NUMERATOR (wave 0) =======================
        const float2* sm2 = (const float2*)sm;
        const int u0 = lane * 4;
        int e[4], ep[4];
        {
            const int base = b * L;
#pragma unroll
            for (int k = 0; k < 4; ++k) {
                int u = u0 + k;
                e[k] = targets[base + ((u < L) ? u : (L - 1))];
            }
            ep[0] = (u0 > 0) ? targets[base + u0 - 1] : e[0];
            ep[1] = e[0]; ep[2] = e[1]; ep[3] = e[2];
        }
        NumC c;
#pragma unroll
        for (int k = 0; k < 4; ++k) {
            c.tee[k] = fexp2(trans[ep[k] * S + e[k]] * LOG2E);
            c.txe[k] = fexp2(trans[(ep[k] + half) * S + e[k]] * LOG2E);
            c.tex[k] = fexp2(trans[e[k] * S + e[k] + half] * LOG2E);
            c.txx[k] = fexp2(trans[(e[k] + half) * S + e[k] + half] * LOG2E);
        }

        float E[4] = {0.f, 0.f, 0.f, 0.f}, X[4] = {0.f, 0.f, 0.f, 0.f};
        int s = 0;
        if (lane == 0) E[0] = fexp2(bos[e[0]] * LOG2E) * sm2[e[0]].x;
        float teeF = (lane == 0) ? 0.0f : c.tee[0];   // fs0 = 1 initially
        float txeF = (lane == 0) ? 0.0f : c.txe[0];

        float2 A[4][4], Bf[4][4];
        int t0 = 1;
#pragma unroll
        for (int q = 0; q < 4; ++q) {          // prime A @ t0..t0+3 (clamped)
            int tq = t0 + q; if (tq > len - 1) tq = len - 1;
#pragma unroll
            for (int k = 0; k < 4; ++k) A[q][k] = sm2[tq * 4 + e[k]];
        }
        cfence();                              // A issued here

        while (t0 + 7 < len) {
#pragma unroll
            for (int q = 0; q < 4; ++q) {      // issue Bf @ t0+4 (in-range)
#pragma unroll
                for (int k = 0; k < 4; ++k)
                    Bf[q][k] = sm2[(t0 + 4 + q) * 4 + e[k]];
            }
            cfence();                          // Bf pinned before A-compute
#pragma unroll
            for (int q = 0; q < 4; ++q) num_step(A[q], E, X, teeF, txeF, c);
#pragma unroll
            for (int q = 0; q < 4; ++q) {      // issue A @ t0+8 (clamped)
                int tq = t0 + 8 + q; if (tq > len - 1) tq = len - 1;
#pragma unroll
                for (int k = 0; k < 4; ++k) A[q][k] = sm2[tq * 4 + e[k]];
            }
            cfence();                          // A' pinned before Bf-compute
#pragma unroll
            for (int q = 0; q < 4; ++q) num_step(Bf[q], E, X, teeF, txeF, c);
            num_boundary(E, X, s, teeF, txeF, lane, c);
            t0 += 8;
        }
        while (t0 < len) {                     // tail (< 8 steps, no renorm)
            float2 p[4];
#pragma unroll
            for (int k = 0; k < 4; ++k) p[k] = sm2[t0 * 4 + e[k]];
            num_step(p, E, X, teeF, txeF, c);
            ++t0;
        }

        const int uf = tlens[b] - 1;
        if (lane == (uf >> 2)) {
            const int k = uf & 3;
            const float fE = (k == 0) ? E[0] : (k == 1) ? E[1] : (k == 2) ? E[2] : E[3];
            const float fX = (k == 0) ? X[0] : (k == 1) ? X[1] : (k == 2) ? X[2] : X[3];
            const int  ek = (k == 0) ? e[0] : (k == 1) ? e[1] : (k == 2) ? e[2] : e[3];
            const float le = (fE > 0.0f)
                ? flog2(fE) + (float)s + eos[ek] * LOG2E : -3.0e38f;
            const float lx = (fX > 0.0f)
                ? flog2(fX) + (float)s + eos[ek + half] * LOG2E : -3.0e38f;
            atomicExch(&ws[b], lse2(le, lx));  // logZ_num, base 2
        }
    } else {
        // ======================= DENOMINATOR (wave 1) =======================
        const int j  = lane & 7;               // mirrored x8 across the wave
        const int jj = ((j & 3) << 1) + (j >> 2);   // float idx of state j
        float Tr[8];
#pragma unroll
        for (int r = 0; r < 8; ++r)
            Tr[r] = fexp2(trans[((j - r) & 7) * S + j] * LOG2E);

        float al = fexp2(bos[j] * LOG2E) * sm[jj];  // t = 0
        int sc = 0;
        int t = 1;
        float c0 = sm[8 + jj];
        float c1 = sm[((2 < len) ? 2 : (len - 1)) * 8 + jj];
        float c2 = sm[((3 < len) ? 3 : (len - 1)) * 8 + jj];
        float c3 = sm[((4 < len) ? 4 : (len - 1)) * 8 + jj];
        cfence();
        while (t + 3 < len) {
            const int t4 = t + 4;
            float n0 = sm[(((t4)     < len) ? (t4)     : (len - 1)) * 8 + jj];
            float n1 = sm[(((t4 + 1) < len) ? (t4 + 1) : (len - 1)) * 8 + jj];
            float n2 = sm[(((t4 + 2) < len) ? (t4 + 2) : (len - 1)) * 8 + jj];
            float n3 = sm[(((t4 + 3) < len) ? (t4 + 3) : (len - 1)) * 8 + jj];
            cfence();                          // next-group loads pinned
            al = den_step(al, c0, Tr);
            al = den_step(al, c1, Tr);
            al = den_step(al, c2, Tr);
            al = den_step(al, c3, Tr);
            float mm = fmaxf(al, fdpp<CTL_ROR(4)>(al));   // renorm every 4
            mm = fmaxf(mm, fdpp<CTL_ROR(2)>(mm));
            mm = fmaxf(mm, fdpp<CTL_ROR(1)>(mm));
            const int ex = (int)(__float_as_uint(mm) >> 23) - 126;
            sc += ex;
            al = ldexpf(al, -ex);
            c0 = n0; c1 = n1; c2 = n2; c3 = n3;
            t += 4;
        }
        while (t < len) { al = den_step(al, sm[t * 8 + jj], Tr); ++t; }

        float f = al * fexp2(eos[j] * LOG2E);
        f += fdpp<CTL_ROR(4)>(f);
        f += fdpp<CTL_ROR(2)>(f);
        f += fdpp<CTL_ROR(1)>(f);
        if (lane == 0)
            atomicExch(&ws[B + b],
                       flog2(fmaxf(f, 1e-36f)) + (float)sc);  // logZ_den, base2
    }

    // ---------------- fused finalize: atomic ticket ----------------
    __syncthreads();                          // both waves done; stores drained
    if (tid == 0) {
        __threadfence();                      // publish ws writes device-wide
        int* cnt = (int*)(ws + 2 * B);        // zeroed by hipMemsetAsync
        const int ticket = atomicAdd(cnt, 1);
        if (ticket == (int)gridDim.x - 1) {   // last block computes the mean
            __threadfence();
            float acc = 0.0f;
            for (int i = 0; i < B; ++i)
                acc += atomicAdd(&ws[B + i], 0.0f) - atomicAdd(&ws[i], 0.0f);
            out[0] = acc * (LN2 / (float)B);
        }
    }
}

extern "C" void kernel_launch(void* const* d_in, const int* in_sizes, int n_in,
                              void* d_out, int out_size, void* d_ws, size_t ws_size,
                              hipStream_t stream)
{
    const float* em      = (const float*)d_in[0];
    const float* trans   = (const float*)d_in[1];
    const float* bos     = (const float*)d_in[2];
    const float* eos     = (const float*)d_in[3];
    const int*   lengths = (const int*)d_in[4];
    const int*   targets = (const int*)d_in[5];
    const int*   tlens   = (const int*)d_in[6];
    float* out = (float*)d_out;
    float* ws  = (float*)d_ws;

    const int B  = in_sizes[4];              // 16
    const int SS = in_sizes[1];              // 64
    int S = 1; while (S * S < SS) ++S;       // 8
    const int T = in_sizes[0] / (B * S);     // 2048
    const int L = in_sizes[5] / B;           // 256

    const size_t shmem = (size_t)T * S * sizeof(float);  // 64 KiB

    // zero the per-batch slots + ticket counter (ws[2B] as int)
    (void)hipMemsetAsync(ws, 0, (2 * B + 1) * sizeof(float), stream);
    hipLaunchKernelGGL(crf_fused, dim3(B), dim3(128), shmem, stream,
                       em, trans, bos, eos, lengths, targets, tlens,
                       ws, out, B, T, S, L);
}

// Round 9
// 162.227 us; speedup vs baseline: 3.2955x; 1.5003x over previous
//
#include <hip/hip_runtime.h>
#include <math.h>

// CTC-CRF NLL: mean_b( logZ_den(b) - logZ_num(b) ), B=16,T=2048,S=8,L=256.
//
// R8: FORWARD/BACKWARD SPLIT — halve the serial chain. At cut tm:
//   logZ = log2( sum_state alpha(tm) * beta(tm) )
// 16 blocks x 256 threads (4 waves, one per SIMD):
//   wave0 num-fwd  t = 1 .. tm         (R7's proven loop, absmax 0)
//   wave1 num-bwd  t = len-1 .. tm+1   (mirror recursion, DPP wave_shl:1)
//   wave2 den-fwd  t = 1 .. tm         (col-dot via row_ror DPPs)
//   wave3 den-bwd  t = len-1 .. tm+1   (row-dot: transposed coeffs)
// Cut-combine via LDS + one __syncthreads, then atomic-ticket finalize.

#define LOG2E 1.4426950408889634f
#define LN2   0.69314718055994531f
#define CTL_WSHL1  0x130            // DPP wave_shl:1  (lane i <- lane i+1; 63->0)
#define CTL_WSHR1  0x138            // DPP wave_shr:1  (lane i <- lane i-1; 0->0)
#define CTL_ROR(r) (0x120 + (r))    // DPP row_ror:r

template <int CTRL>
__device__ __forceinline__ float fdpp(float x) {
    return __int_as_float(__builtin_amdgcn_update_dpp(
        0, __float_as_int(x), CTRL, 0xF, 0xF, true));
}
template <int CTRL>
__device__ __forceinline__ int idpp(int x) {
    return __builtin_amdgcn_update_dpp(0, x, CTRL, 0xF, 0xF, true);
}
__device__ __forceinline__ void cfence() { asm volatile("" ::: "memory"); }

__device__ __forceinline__ float fexp2(float x) {
#if __has_builtin(__builtin_amdgcn_exp2f)
    return __builtin_amdgcn_exp2f(x);
#else
    return exp2f(x);
#endif
}
__device__ __forceinline__ float flog2(float x) {
#if __has_builtin(__builtin_amdgcn_logf)
    return __builtin_amdgcn_logf(x);
#else
    return __log2f(x);
#endif
}
__device__ __forceinline__ float lse2(float a, float b) {   // log2(2^a+2^b)
    float m = fmaxf(a, b);
    float d = fminf(a, b) - m;
    return m + flog2(1.0f + fexp2(d));
}

struct NumC { float tee[4], txe[4], tex[4], txx[4]; };

// ---------------- forward numerator step (R7, proven) ----------------
__device__ __forceinline__ void numf_step(const float2* p, float* E, float* X,
                                          float teeF, float txeF, const NumC& c) {
    float nbE = fdpp<CTL_WSHR1>(E[3]);
    float nbX = fdpp<CTL_WSHR1>(X[3]);
    float nE0 = p[0].x * fmaf(nbE,  teeF,     nbX  * txeF);
    float nE1 = p[1].x * fmaf(E[0], c.tee[1], X[0] * c.txe[1]);
    float nE2 = p[2].x * fmaf(E[1], c.tee[2], X[1] * c.txe[2]);
    float nE3 = p[3].x * fmaf(E[2], c.tee[3], X[2] * c.txe[3]);
    float nX0 = p[0].y * fmaf(E[0], c.tex[0], X[0] * c.txx[0]);
    float nX1 = p[1].y * fmaf(E[1], c.tex[1], X[1] * c.txx[1]);
    float nX2 = p[2].y * fmaf(E[2], c.tex[2], X[2] * c.txx[2]);
    float nX3 = p[3].y * fmaf(E[3], c.tex[3], X[3] * c.txx[3]);
    E[0] = nE0; E[1] = nE1; E[2] = nE2; E[3] = nE3;
    X[0] = nX0; X[1] = nX1; X[2] = nX2; X[3] = nX3;
}

__device__ __forceinline__ void numf_boundary(float* E, float* X, int& s,
                                              float& teeF, float& txeF,
                                              int lane, const NumC& c) {
    float m = fmaxf(fmaxf(fmaxf(E[0], E[1]), fmaxf(E[2], E[3])),
                    fmaxf(fmaxf(X[0], X[1]), fmaxf(X[2], X[3])));
    const bool live = (m > 0.0f);
    const int ex = live ? ((int)(__float_as_uint(m) >> 23) - 126) : 0;
    s += ex;
    const int bs = idpp<CTL_WSHR1>(s);
    if (!live) s = bs;
    int d = (lane == 0) ? 0 : (bs - s);
    const int extra = (d > 30) ? d : 0;
    s += extra; d -= extra;
    const float fsc = ldexpf(1.0f, -(ex + extra));
#pragma unroll
    for (int k = 0; k < 4; ++k) { E[k] *= fsc; X[k] *= fsc; }
    const float fs0 = (lane == 0) ? 0.0f : ldexpf(1.0f, d);
    teeF = c.tee[0] * fs0;
    txeF = c.txe[0] * fs0;
}

// ---------------- backward numerator step ----------------
// bE[u](t-1) = tex_u*em_x[u](t)*bX[u](t) + teeN_u*em_e[u+1](t)*bE[u+1](t)
// bX[u](t-1) = txx_u*em_x[u](t)*bX[u](t) + txeN_u*em_e[u+1](t)*bE[u+1](t)
__device__ __forceinline__ void numb_step(const float2* p, float* bE, float* bX,
                                          const float* tex, const float* txx,
                                          const float* teeN, const float* txeN,
                                          float teeN3F, float txeN3F) {
    float mm0 = p[0].x * bE[0];
    float mm1 = p[1].x * bE[1];
    float mm2 = p[2].x * bE[2];
    float mm3 = p[3].x * bE[3];
    float m10 = p[0].y * bX[0];
    float m11 = p[1].y * bX[1];
    float m12 = p[2].y * bX[2];
    float m13 = p[3].y * bX[3];
    float mup = fdpp<CTL_WSHL1>(mm0);        // lane+1's mm0; lane63 -> 0
    float nE0 = fmaf(tex[0], m10, teeN[0] * mm1);
    float nE1 = fmaf(tex[1], m11, teeN[1] * mm2);
    float nE2 = fmaf(tex[2], m12, teeN[2] * mm3);
    float nE3 = fmaf(tex[3], m13, teeN3F   * mup);
    float nX0 = fmaf(txx[0], m10, txeN[0] * mm1);
    float nX1 = fmaf(txx[1], m11, txeN[1] * mm2);
    float nX2 = fmaf(txx[2], m12, txeN[2] * mm3);
    float nX3 = fmaf(txx[3], m13, txeN3F   * mup);
    bE[0] = nE0; bE[1] = nE1; bE[2] = nE2; bE[3] = nE3;
    bX[0] = nX0; bX[1] = nX1; bX[2] = nX2; bX[3] = nX3;
}

__device__ __forceinline__ void numb_boundary(float* bE, float* bX, int& s,
                                              float& teeN3F, float& txeN3F,
                                              int lane, float teeN3, float txeN3) {
    float m = fmaxf(fmaxf(fmaxf(bE[0], bE[1]), fmaxf(bE[2], bE[3])),
                    fmaxf(fmaxf(bX[0], bX[1]), fmaxf(bX[2], bX[3])));
    const bool live = (m > 0.0f);
    const int ex = live ? ((int)(__float_as_uint(m) >> 23) - 126) : 0;
    s += ex;
    const int bs = idpp<CTL_WSHL1>(s);       // lane+1's scale (lane63 -> 0)
    if (!live) s = bs;
    int d = (lane == 63) ? 0 : (bs - s);
    const int extra = (d > 30) ? d : 0;
    s += extra; d -= extra;
    const float fsc = ldexpf(1.0f, -(ex + extra));
#pragma unroll
    for (int k = 0; k < 4; ++k) { bE[k] *= fsc; bX[k] *= fsc; }
    const float fs = (lane == 63) ? 0.0f : ldexpf(1.0f, d);
    teeN3F = teeN3 * fs;
    txeN3F = txeN3 * fs;
}

// ---------------- denominator steps ----------------
__device__ __forceinline__ float denf_step(float al, float emt, const float* Tr) {
    float v1 = fdpp<CTL_ROR(1)>(al);
    float v2 = fdpp<CTL_ROR(2)>(al);
    float v3 = fdpp<CTL_ROR(3)>(al);
    float v4 = fdpp<CTL_ROR(4)>(al);
    float v5 = fdpp<CTL_ROR(5)>(al);
    float v6 = fdpp<CTL_ROR(6)>(al);
    float v7 = fdpp<CTL_ROR(7)>(al);
    float q0 = fmaf(v1, Tr[1], al * Tr[0]);
    float q1 = fmaf(v3, Tr[3], v2 * Tr[2]);
    float q2 = fmaf(v5, Tr[5], v4 * Tr[4]);
    float q3 = fmaf(v7, Tr[7], v6 * Tr[6]);
    return ((q0 + q1) + (q2 + q3)) * emt;
}
// backward: g = al*em(t); beta_i = sum_r T[i][(i+r)&7] g_{(i+r)&7};
// g_{(i+r)} = ror(8-r) of g (8-periodic data).
__device__ __forceinline__ float denb_step(float al, float emt, const float* TrB) {
    float g  = al * emt;
    float v1 = fdpp<CTL_ROR(7)>(g);   // g_{i+1}
    float v2 = fdpp<CTL_ROR(6)>(g);
    float v3 = fdpp<CTL_ROR(5)>(g);
    float v4 = fdpp<CTL_ROR(4)>(g);
    float v5 = fdpp<CTL_ROR(3)>(g);
    float v6 = fdpp<CTL_ROR(2)>(g);
    float v7 = fdpp<CTL_ROR(1)>(g);
    float q0 = fmaf(v1, TrB[1], g * TrB[0]);
    float q1 = fmaf(v3, TrB[3], v2 * TrB[2]);
    float q2 = fmaf(v5, TrB[5], v4 * TrB[4]);
    float q3 = fmaf(v7, TrB[7], v6 * TrB[6]);
    return (q0 + q1) + (q2 + q3);
}

extern "C" __global__ void __launch_bounds__(256)
crf_fused(const float* __restrict__ em, const float* __restrict__ trans,
          const float* __restrict__ bos, const float* __restrict__ eos,
          const int* __restrict__ lengths, const int* __restrict__ targets,
          const int* __restrict__ tlens,
          float* __restrict__ ws, float* __restrict__ out,
          int B, int T, int S, int L)
{
    extern __shared__ float sm[];            // [0, T*8): emission pairs
    const int b    = blockIdx.x;
    const int tid  = threadIdx.x;
    const int half = S >> 1;                 // = 4
    const float* gem = em + (size_t)b * T * S;
    const int len = lengths[b];
    const int tm  = (len - 1) >> 1;          // cut point

    // LDS scratch past the emission block
    float* numF  = sm + T * 8;               // 64*8
    float* numB  = numF + 512;               // 64*8
    int*   numFs = (int*)(numB + 512);       // 64
    int*   numBs = numFs + 64;               // 64
    float* denF  = (float*)(numBs + 64);     // 8
    float* denB  = denF + 8;                 // 8
    int*   denFs = (int*)(denB + 8);         // 8
    int*   denBs = denFs + 8;                // 8

    // ---- stage emissions once, interleaved base-2 probs ----
    for (int t = tid; t < T; t += 256) {
        const float4* gr = (const float4*)(gem + t * S);
        float4 a = gr[0], c4 = gr[1];
        float4 w0, w1;
        w0.x = fexp2(a.x * LOG2E); w0.y = fexp2(c4.x * LOG2E);
        w0.z = fexp2(a.y * LOG2E); w0.w = fexp2(c4.y * LOG2E);
        w1.x = fexp2(a.z * LOG2E); w1.y = fexp2(c4.z * LOG2E);
        w1.z = fexp2(a.w * LOG2E); w1.w = fexp2(c4.w * LOG2E);
        ((float4*)sm)[t * 2]     = w0;
        ((float4*)sm)[t * 2 + 1] = w1;
    }
    __syncthreads();

    const int wv   = tid >> 6;
    const int lane = tid & 63;
    const float2* sm2 = (const float2*)sm;

    if (wv == 0) {
        // =================== NUMERATOR FORWARD: t = 1..tm ===================
        const int u0 = lane * 4;
        int e[4], ep[4];
        const int base = b * L;
#pragma unroll
        for (int k = 0; k < 4; ++k) {
            int u = u0 + k;
            e[k] = targets[base + ((u < L) ? u : (L - 1))];
        }
        ep[0] = (u0 > 0) ? targets[base + u0 - 1] : e[0];
        ep[1] = e[0]; ep[2] = e[1]; ep[3] = e[2];
        NumC c;
#pragma unroll
        for (int k = 0; k < 4; ++k) {
            c.tee[k] = fexp2(trans[ep[k] * S + e[k]] * LOG2E);
            c.txe[k] = fexp2(trans[(ep[k] + half) * S + e[k]] * LOG2E);
            c.tex[k] = fexp2(trans[e[k] * S + e[k] + half] * LOG2E);
            c.txx[k] = fexp2(trans[(e[k] + half) * S + e[k] + half] * LOG2E);
        }
        float E[4] = {0.f,0.f,0.f,0.f}, X[4] = {0.f,0.f,0.f,0.f};
        int s = 0;
        if (lane == 0) E[0] = fexp2(bos[e[0]] * LOG2E) * sm2[e[0]].x;
        float teeF = (lane == 0) ? 0.0f : c.tee[0];
        float txeF = (lane == 0) ? 0.0f : c.txe[0];

        float2 A[4][4], Bf[4][4];
        int t0 = 1;
#pragma unroll
        for (int q = 0; q < 4; ++q) {
            int tq = t0 + q; if (tq > tm) tq = (tm > 0) ? tm : 0;
#pragma unroll
            for (int k = 0; k < 4; ++k) A[q][k] = sm2[tq * 4 + e[k]];
        }
        cfence();
        while (t0 + 7 <= tm) {
#pragma unroll
            for (int q = 0; q < 4; ++q)
#pragma unroll
                for (int k = 0; k < 4; ++k)
                    Bf[q][k] = sm2[(t0 + 4 + q) * 4 + e[k]];
            cfence();
#pragma unroll
            for (int q = 0; q < 4; ++q) numf_step(A[q], E, X, teeF, txeF, c);
#pragma unroll
            for (int q = 0; q < 4; ++q) {
                int tq = t0 + 8 + q; if (tq > tm) tq = tm;
#pragma unroll
                for (int k = 0; k < 4; ++k) A[q][k] = sm2[tq * 4 + e[k]];
            }
            cfence();
#pragma unroll
            for (int q = 0; q < 4; ++q) numf_step(Bf[q], E, X, teeF, txeF, c);
            numf_boundary(E, X, s, teeF, txeF, lane, c);
            t0 += 8;
        }
        while (t0 <= tm) {
            float2 p[4];
#pragma unroll
            for (int k = 0; k < 4; ++k) p[k] = sm2[t0 * 4 + e[k]];
            numf_step(p, E, X, teeF, txeF, c);
            ++t0;
        }
#pragma unroll
        for (int k = 0; k < 4; ++k) {
            numF[lane * 8 + k]     = E[k];
            numF[lane * 8 + 4 + k] = X[k];
        }
        numFs[lane] = s;
    } else if (wv == 1) {
        // =================== NUMERATOR BACKWARD: t = len-1..tm+1 ===========
        const int u0 = lane * 4;
        int e[5];
        const int base = b * L;
#pragma unroll
        for (int k = 0; k < 5; ++k) {
            int u = u0 + k;
            e[k] = targets[base + ((u < L) ? u : (L - 1))];
        }
        float tex[4], txx[4], teeN[4], txeN[4];
#pragma unroll
        for (int k = 0; k < 4; ++k) {
            tex[k]  = fexp2(trans[e[k] * S + e[k] + half] * LOG2E);
            txx[k]  = fexp2(trans[(e[k] + half) * S + e[k] + half] * LOG2E);
            teeN[k] = fexp2(trans[e[k] * S + e[k + 1]] * LOG2E);
            txeN[k] = fexp2(trans[(e[k] + half) * S + e[k + 1]] * LOG2E);
        }
        if (lane == 63) { teeN[3] = 0.0f; txeN[3] = 0.0f; }  // u=L-1: no succ
        float bE[4] = {0.f,0.f,0.f,0.f}, bX[4] = {0.f,0.f,0.f,0.f};
        const int uf = tlens[b] - 1;
        if (lane == (uf >> 2)) {
            const int kf = uf & 3;
            const int ef = e[kf];
            bE[kf] = fexp2(eos[ef] * LOG2E);
            bX[kf] = fexp2(eos[ef + half] * LOG2E);
        }
        int s = 0;
        float teeN3F = teeN[3], txeN3F = txeN[3];

        float2 A[4][4], Bf[4][4];
        int t1 = len - 1;                    // process rows t1 descending
        const int tlo = tm + 1;
#pragma unroll
        for (int q = 0; q < 4; ++q) {
            int tq = t1 - q; if (tq < tlo) tq = tlo;
#pragma unroll
            for (int k = 0; k < 4; ++k) A[q][k] = sm2[tq * 4 + e[k]];
        }
        cfence();
        while (t1 - 7 >= tlo) {
#pragma unroll
            for (int q = 0; q < 4; ++q)
#pragma unroll
                for (int k = 0; k < 4; ++k)
                    Bf[q][k] = sm2[(t1 - 4 - q) * 4 + e[k]];
            cfence();
#pragma unroll
            for (int q = 0; q < 4; ++q)
                numb_step(A[q], bE, bX, tex, txx, teeN, txeN, teeN3F, txeN3F);
#pragma unroll
            for (int q = 0; q < 4; ++q) {
                int tq = t1 - 8 - q; if (tq < tlo) tq = tlo;
#pragma unroll
                for (int k = 0; k < 4; ++k) A[q][k] = sm2[tq * 4 + e[k]];
            }
            cfence();
#pragma unroll
            for (int q = 0; q < 4; ++q)
                numb_step(Bf[q], bE, bX, tex, txx, teeN, txeN, teeN3F, txeN3F);
            numb_boundary(bE, bX, s, teeN3F, txeN3F, lane, teeN[3], txeN[3]);
            t1 -= 8;
        }
        while (t1 >= tlo) {
            float2 p[4];
#pragma unroll
            for (int k = 0; k < 4; ++k) p[k] = sm2[t1 * 4 + e[k]];
            numb_step(p, bE, bX, tex, txx, teeN, txeN, teeN3F, txeN3F);
            --t1;
        }
#pragma unroll
        for (int k = 0; k < 4; ++k) {
            numB[lane * 8 + k]     = bE[k];
            numB[lane * 8 + 4 + k] = bX[k];
        }
        numBs[lane] = s;
    } else if (wv == 2) {
        // =================== DENOMINATOR FORWARD: t = 1..tm ================
        const int j  = lane & 7;
        const int jj = ((j & 3) << 1) + (j >> 2);
        float Tr[8];
#pragma unroll
        for (int r = 0; r < 8; ++r)
            Tr[r] = fexp2(trans[((j - r) & 7) * S + j] * LOG2E);
        float al = fexp2(bos[j] * LOG2E) * sm[jj];
        int sc = 0;
        int t = 1;
        while (t + 3 <= tm) {
            float c0 = sm[t * 8 + jj];
            float c1 = sm[(t + 1) * 8 + jj];
            float c2 = sm[(t + 2) * 8 + jj];
            float c3 = sm[(t + 3) * 8 + jj];
            cfence();
            al = denf_step(al, c0, Tr);
            al = denf_step(al, c1, Tr);
            al = denf_step(al, c2, Tr);
            al = denf_step(al, c3, Tr);
            float mm = fmaxf(al, fdpp<CTL_ROR(4)>(al));
            mm = fmaxf(mm, fdpp<CTL_ROR(2)>(mm));
            mm = fmaxf(mm, fdpp<CTL_ROR(1)>(mm));
            const int ex = (int)(__float_as_uint(mm) >> 23) - 126;
            sc += ex;
            al = ldexpf(al, -ex);
            t += 4;
        }
        while (t <= tm) { al = denf_step(al, sm[t * 8 + jj], Tr); ++t; }
        if (lane < 8) { denF[j] = al; denFs[j] = sc; }
    } else {
        // =================== DENOMINATOR BACKWARD: t = len-1..tm+1 =========
        const int j  = lane & 7;
        const int jj = ((j & 3) << 1) + (j >> 2);
        float TrB[8];
#pragma unroll
        for (int r = 0; r < 8; ++r)
            TrB[r] = fexp2(trans[j * S + ((j + r) & 7)] * LOG2E);
        float al = fexp2(eos[j] * LOG2E);
        int sc = 0;
        int t = len - 1;
        const int tlo = tm + 1;
        while (t - 3 >= tlo) {
            float c0 = sm[t * 8 + jj];
            float c1 = sm[(t - 1) * 8 + jj];
            float c2 = sm[(t - 2) * 8 + jj];
            float c3 = sm[(t - 3) * 8 + jj];
            cfence();
            al = denb_step(al, c0, TrB);
            al = denb_step(al, c1, TrB);
            al = denb_step(al, c2, TrB);
            al = denb_step(al, c3, TrB);
            float mm = fmaxf(al, fdpp<CTL_ROR(4)>(al));
            mm = fmaxf(mm, fdpp<CTL_ROR(2)>(mm));
            mm = fmaxf(mm, fdpp<CTL_ROR(1)>(mm));
            const int ex = (int)(__float_as_uint(mm) >> 23) - 126;
            sc += ex;
            al = ldexpf(al, -ex);
            t -= 4;
        }
        while (t >= tlo) { al = denb_step(al, sm[t * 8 + jj], TrB); --t; }
        if (lane < 8) { denB[j] = al; denBs[j] = sc; }
    }

    __syncthreads();                         // all four waves published state

    if (wv == 0) {
        // ---- numerator combine: logZ = log2 sum_u aE*bE + aX*bX ----
        float v = 0.0f;
#pragma unroll
        for (int k = 0; k < 8; ++k)
            v = fmaf(numF[lane * 8 + k], numB[lane * 8 + k], v);
        const int st = numFs[lane] + numBs[lane];
        float part = (v > 0.0f) ? (flog2(v) + (float)st) : -3.0e38f;
#pragma unroll
        for (int o = 1; o < 64; o <<= 1)
            part = lse2(part, __shfl_xor(part, o, 64));
        if (lane == 0) ws[b] = part;         // logZ_num, base 2
    } else if (wv == 2) {
        // ---- denominator combine: logZ = log2 sum_j alpha_j beta_j ----
        if (lane < 8) {
            const float a = fmaxf(denF[lane], 1e-37f);
            const float bb = fmaxf(denB[lane], 1e-37f);
            float part = flog2(a) + flog2(bb)
                       + (float)(denFs[lane] + denBs[lane]);
            part = lse2(part, __shfl_xor(part, 1, 64));
            part = lse2(part, __shfl_xor(part, 2, 64));
            part = lse2(part, __shfl_xor(part, 4, 64));
            if (lane == 0) ws[B + b] = part; // logZ_den, base 2
        }
    }

    // ---------------- fused finalize: atomic ticket ----------------
    __syncthreads();
    if (tid == 0) {
        __threadfence();
        int* cnt = (int*)(ws + 2 * B);       // zeroed by hipMemsetAsync
        const int ticket = atomicAdd(cnt, 1);
        if (ticket == (int)gridDim.x - 1) {
            __threadfence();
            float acc = 0.0f;
            for (int i = 0; i < B; ++i)
                acc += atomicAdd(&ws[B + i], 0.0f) - atomicAdd(&ws[i], 0.0f);
            out[0] = acc * (LN2 / (float)B);
        }
    }
}

extern "C" void kernel_launch(void* const* d_in, const int* in_sizes, int n_in,
                              void* d_out, int out_size, void* d_ws, size_t ws_size,
                              hipStream_t stream)
{
    const float* em      = (const float*)d_in[0];
    const float* trans   = (const float*)d_in[1];
    const float* bos     = (const float*)d_in[2];
    const float* eos     = (const float*)d_in[3];
    const int*   lengths = (const int*)d_in[4];
    const int*   targets = (const int*)d_in[5];
    const int*   tlens   = (const int*)d_in[6];
    float* out = (float*)d_out;
    float* ws  = (float*)d_ws;

    const int B  = in_sizes[4];              // 16
    const int SS = in_sizes[1];              // 64
    int S = 1; while (S * S < SS) ++S;       // 8
    const int T = in_sizes[0] / (B * S);     // 2048
    const int L = in_sizes[5] / B;           // 256

    // emissions (T*8) + fwd/bwd scratch (~1.2K floats)
    const size_t shmem = (size_t)(T * 8 + 1280) * sizeof(float);

    (void)hipMemsetAsync(ws, 0, (2 * B + 1) * sizeof(float), stream);
    hipLaunchKernelGGL(crf_fused, dim3(B), dim3(256), shmem, stream,
                       em, trans, bos, eos, lengths, targets, tlens,
                       ws, out, B, T, S, L);
}